// Round 14
// baseline (94.849 us; speedup 1.0000x reference)
//
#include <hip/hip_runtime.h>

typedef __attribute__((ext_vector_type(8))) short short8;
typedef __attribute__((ext_vector_type(4))) float f32x4;

#define D_KV   64
#define SEQ    4096
#define NBATCH 4
#define DMODEL 1024

static __device__ __forceinline__ unsigned short f32_to_bf16(float f) {
  unsigned u = __builtin_bit_cast(unsigned, f);
  u = (u + 0x7FFFu + ((u >> 16) & 1u)) >> 16;  // round-nearest-even
  return (unsigned short)u;
}

// ---------------- kernel 1: weights f32 -> bf16, MFMA-fragment order --------
__global__ __launch_bounds__(256) void wcvt_kernel(
    const float* __restrict__ wq, const float* __restrict__ wk,
    const float* __restrict__ wv, unsigned short* __restrict__ wfrag) {
  const int fid = blockIdx.x * 256 + threadIdx.x;  // 0..24575
  const int nt = fid >> 11, ks = (fid >> 6) & 31, lane = fid & 63;
  const int l16 = lane & 15, lq = lane >> 4;
  const float* w = (nt < 4) ? wq : (nt < 8) ? wk : wv;
  const float* src = w + ((nt & 3) * 16 + l16) * DMODEL + ks * 32 + lq * 8;
  short8 v;
#pragma unroll
  for (int j = 0; j < 8; ++j) v[j] = (short)f32_to_bf16(src[j]);
  *reinterpret_cast<short8*>(wfrag + (long)fid * 8) = v;
}

// ---------------- PROBE W: proj's weight-load stream, isolated --------------
// Same grid (512 blocks), same per-wave addresses as production proj.
// 4 repetitions (memory-clobber between reps defeats load CSE).
__global__ __launch_bounds__(256, 1) void probe_w(
    const unsigned short* __restrict__ wfrag, unsigned short* __restrict__ sink) {
  const int tid = threadIdx.x, lane = tid & 63, wave = tid >> 6;
  const unsigned short* wbase = wfrag + (long)(3 * wave) * 16384 + lane * 8;
  short8 acc = {0, 0, 0, 0, 0, 0, 0, 0};
  for (int r = 0; r < 4; ++r) {
#pragma unroll
    for (int ck = 0; ck < 8; ++ck)
#pragma unroll
      for (int j = 0; j < 12; ++j) {
        const short8 b = *reinterpret_cast<const short8*>(
            wbase + (long)(j >> 2) * 16384 + (ck * 4 + (j & 3)) * 512);
        acc ^= b;
      }
    asm volatile("" ::: "memory");
  }
  *reinterpret_cast<short8*>(sink + ((long)blockIdx.x * 256 + tid) * 8) = acc;
}

// ---------------- PROBE X: proj's x staging + A-fragment reads, isolated ----
__global__ __launch_bounds__(256, 1) void probe_x(
    const float* __restrict__ x, unsigned short* __restrict__ sink) {
  __shared__ __align__(16) unsigned short lds_x[32 * 1024];  // 64KB swizzled
  const int tid = threadIdx.x, lane = tid & 63;
  const int l16 = lane & 15, lq = lane >> 4;
  const long rowbase = (long)blockIdx.x * 32;
  unsigned char* lx = (unsigned char*)lds_x;
  short8 acc = {0, 0, 0, 0, 0, 0, 0, 0};
  for (int r = 0; r < 4; ++r) {
    {
      const int srow = tid >> 3, scol = (tid & 7) * 16;
      const float* xrow = x + (rowbase + srow) * DMODEL + scol;
      const int swz = (srow & 7) << 4;
      unsigned char* lbase = lx + srow * 2048;
#pragma unroll
      for (int s = 0; s < 8; ++s) {
        const f32x4 f0 = *reinterpret_cast<const f32x4*>(xrow + s * 128);
        const f32x4 f1 = *reinterpret_cast<const f32x4*>(xrow + s * 128 + 4);
        const f32x4 f2 = *reinterpret_cast<const f32x4*>(xrow + s * 128 + 8);
        const f32x4 f3 = *reinterpret_cast<const f32x4*>(xrow + s * 128 + 12);
        short8 s0, s1;
#pragma unroll
        for (int j = 0; j < 4; ++j) {
          s0[j]     = (short)f32_to_bf16(f0[j]);
          s0[4 + j] = (short)f32_to_bf16(f1[j]);
          s1[j]     = (short)f32_to_bf16(f2[j]);
          s1[4 + j] = (short)f32_to_bf16(f3[j]);
        }
        const int bcol = scol * 2 + s * 256;
        *reinterpret_cast<short8*>(lbase + (bcol ^ swz)) = s0;
        *reinterpret_cast<short8*>(lbase + ((bcol + 16) ^ swz)) = s1;
      }
    }
    __syncthreads();
#pragma unroll
    for (int ck = 0; ck < 8; ++ck)
#pragma unroll
      for (int kc = 0; kc < 4; ++kc)
#pragma unroll
        for (int sub = 0; sub < 2; ++sub) {
          const int row = sub * 16 + l16;
          acc ^= *reinterpret_cast<const short8*>(
              lx + row * 2048 +
              (((ck * 4 + kc) * 64 + lq * 16) ^ ((row & 7) << 4)));
        }
    __syncthreads();
    asm volatile("" ::: "memory");
  }
  *reinterpret_cast<short8*>(sink + ((long)blockIdx.x * 256 + tid) * 8) = acc;
}

// ---------------- kernel 2: QKV projection (R12, best-known-good) -----------
__global__ __launch_bounds__(256, 1) void qkv_proj_kernel(
    const float* __restrict__ x, const unsigned short* __restrict__ wfrag,
    const float* __restrict__ bq, const float* __restrict__ bk,
    const float* __restrict__ bv,
    unsigned short* __restrict__ Qf, unsigned short* __restrict__ Kf,
    unsigned short* __restrict__ Vf) {
  __shared__ __align__(16) unsigned short lds_x[32 * 1024];  // 64KB swizzled
  const int tid = threadIdx.x, lane = tid & 63, wave = tid >> 6;
  const int l16 = lane & 15, lq = lane >> 4;
  const long rowbase = (long)blockIdx.x * 32;
  unsigned char* lx = (unsigned char*)lds_x;

  {
    const int srow = tid >> 3, scol = (tid & 7) * 16;
    const float* xrow = x + (rowbase + srow) * DMODEL + scol;
    const int swz = (srow & 7) << 4;
    unsigned char* lbase = lx + srow * 2048;
#pragma unroll
    for (int s = 0; s < 8; ++s) {
      const f32x4 f0 = *reinterpret_cast<const f32x4*>(xrow + s * 128);
      const f32x4 f1 = *reinterpret_cast<const f32x4*>(xrow + s * 128 + 4);
      const f32x4 f2 = *reinterpret_cast<const f32x4*>(xrow + s * 128 + 8);
      const f32x4 f3 = *reinterpret_cast<const f32x4*>(xrow + s * 128 + 12);
      short8 s0, s1;
#pragma unroll
      for (int j = 0; j < 4; ++j) {
        s0[j]     = (short)f32_to_bf16(f0[j]);
        s0[4 + j] = (short)f32_to_bf16(f1[j]);
        s1[j]     = (short)f32_to_bf16(f2[j]);
        s1[4 + j] = (short)f32_to_bf16(f3[j]);
      }
      const int bcol = scol * 2 + s * 256;
      *reinterpret_cast<short8*>(lbase + (bcol ^ swz)) = s0;
      *reinterpret_cast<short8*>(lbase + ((bcol + 16) ^ swz)) = s1;
    }
  }
  __syncthreads();

  const unsigned short* wbase = wfrag + (long)(3 * wave) * 16384 + lane * 8;

  short8 bw[12];
#pragma unroll
  for (int j = 0; j < 12; ++j)
    bw[j] = *reinterpret_cast<const short8*>(
        wbase + (long)(j >> 2) * 16384 + (j & 3) * 512);

  f32x4 acc[3][2];
#pragma unroll
  for (int i = 0; i < 3; ++i)
#pragma unroll
    for (int s = 0; s < 2; ++s) acc[i][s] = (f32x4){0.f, 0.f, 0.f, 0.f};

#pragma unroll
  for (int ck = 0; ck < 8; ++ck) {
    short8 bn[12];
    if (ck < 7) {
#pragma unroll
      for (int j = 0; j < 12; ++j)
        bn[j] = *reinterpret_cast<const short8*>(
            wbase + (long)(j >> 2) * 16384 + ((ck + 1) * 4 + (j & 3)) * 512);
    }
    short8 a[4][2];
#pragma unroll
    for (int kc = 0; kc < 4; ++kc)
#pragma unroll
      for (int sub = 0; sub < 2; ++sub) {
        const int row = sub * 16 + l16;
        a[kc][sub] = *reinterpret_cast<const short8*>(
            lx + row * 2048 +
            (((ck * 4 + kc) * 64 + lq * 16) ^ ((row & 7) << 4)));
      }
#pragma unroll
    for (int kc = 0; kc < 4; ++kc)
#pragma unroll
      for (int i = 0; i < 3; ++i) {
        acc[i][0] = __builtin_amdgcn_mfma_f32_16x16x32_bf16(
            a[kc][0], bw[i * 4 + kc], acc[i][0], 0, 0, 0);
        acc[i][1] = __builtin_amdgcn_mfma_f32_16x16x32_bf16(
            a[kc][1], bw[i * 4 + kc], acc[i][1], 0, 0, 0);
      }
    if (ck < 7) {
#pragma unroll
      for (int j = 0; j < 12; ++j) bw[j] = bn[j];
    }
  }

  __syncthreads();  // reuse lds_x as out-stage
  unsigned short* lo = lds_x;

#pragma unroll
  for (int i = 0; i < 3; ++i) {
    const int nt = 3 * wave + i;
    const int mat = nt >> 2;
    const int dcol = ((nt & 3) << 4) | l16;
    const float bias = (mat == 0 ? bq : mat == 1 ? bk : bv)[dcol];
    const int c = dcol >> 5, lqp = (dcol >> 3) & 3, jj = dcol & 7;
#pragma unroll
    for (int sub = 0; sub < 2; ++sub)
#pragma unroll
      for (int rr = 0; rr < 4; ++rr) {
        const int tl = sub * 16 + lq * 4 + rr;
        const float sum = acc[i][sub][rr] + bias;
        if (mat == 0) {
          lo[(((tl >> 4) * 2 + c) * 64 + lqp * 16 + (tl & 15)) * 8 + jj] =
              f32_to_bf16(sum * 0.125f);
        } else if (mat == 1) {
          lo[2048 + (((tl >> 4) * 2 + c) * 64 + lqp * 16 + (tl & 15)) * 8 + jj] =
              f32_to_bf16(sum);
        } else {
          lo[4096 + (nt & 3) * 512 +
             (((tl >> 3) & 3) * 16 + (dcol & 15)) * 8 + (tl & 7)] =
              f32_to_bf16(sum);
        }
      }
  }
  __syncthreads();
  {
    const long qb = (rowbase >> 4) * 1024;
    const int g = tid >> 6;
    const long vb = (((rowbase >> 6) * 4 + g) * 2 + ((rowbase >> 5) & 1)) * 512;
    *reinterpret_cast<short8*>(Qf + qb + tid * 8) =
        *reinterpret_cast<const short8*>(lo + tid * 8);
    *reinterpret_cast<short8*>(Kf + qb + tid * 8) =
        *reinterpret_cast<const short8*>(lo + 2048 + tid * 8);
    *reinterpret_cast<short8*>(Vf + vb + (tid & 63) * 8) =
        *reinterpret_cast<const short8*>(lo + 4096 + tid * 8);
  }
}

// ---------------- kernel 3: causal flash attention (R4-proven) --------------
__global__ __launch_bounds__(256) void attn_kernel(
    const unsigned short* __restrict__ Qf, const unsigned short* __restrict__ Kf,
    const unsigned short* __restrict__ Vf, float* __restrict__ out) {
  __shared__ __align__(16) unsigned short p_lds[4][16][72];
  __shared__ __align__(16) float lds_o[4][16][68];
  __shared__ float lds_ml[4][16][2];
  __shared__ float lds_gl[16];

  const int tid = threadIdx.x;
  const int lane = tid & 63;
  const int wave = tid >> 6;
  const int l16 = lane & 15, lq = lane >> 4;
  const int b = blockIdx.y;
  const int tile = 255 - blockIdx.x;
  const int qbase = tile * 16;
  const long qrow = (long)b * SEQ + qbase;

  short8 qf[2];
#pragma unroll
  for (int c = 0; c < 2; ++c)
    qf[c] = *reinterpret_cast<const short8*>(
        Qf + ((qrow >> 4) * 2 + c) * 512 + lane * 8);

  f32x4 o[4];
#pragma unroll
  for (int dt = 0; dt < 4; ++dt) o[dt] = (f32x4){0.f, 0.f, 0.f, 0.f};
  float m = -INFINITY, ell = 0.f;

  const long ktile0 = (long)b * 64;
  const int nkv = qbase / 64 + 1;
  for (int kt = wave; kt < nkv; kt += 4) {
    const int kvbase = kt * 64;
    const unsigned short* kb = Kf + (ktile0 + kt) * 4096 + lane * 8;
    const unsigned short* vb = Vf + (ktile0 + kt) * 4096 + lane * 8;
    f32x4 s[4];
#pragma unroll
    for (int ct = 0; ct < 4; ++ct) s[ct] = (f32x4){0.f, 0.f, 0.f, 0.f};
#pragma unroll
    for (int ct = 0; ct < 4; ++ct)
#pragma unroll
      for (int c = 0; c < 2; ++c) {
        short8 kf = *reinterpret_cast<const short8*>(kb + (ct * 2 + c) * 512);
        s[ct] = __builtin_amdgcn_mfma_f32_16x16x32_bf16(kf, qf[c], s[ct], 0, 0, 0);
      }
    if (kt == nkv - 1) {
      const int qg = qbase + l16;
#pragma unroll
      for (int ct = 0; ct < 4; ++ct)
#pragma unroll
        for (int r = 0; r < 4; ++r)
          if (kvbase + ct * 16 + lq * 4 + r > qg) s[ct][r] = -INFINITY;
    }
    float mx = -INFINITY;
#pragma unroll
    for (int ct = 0; ct < 4; ++ct)
#pragma unroll
      for (int r = 0; r < 4; ++r) mx = fmaxf(mx, s[ct][r]);
    mx = fmaxf(mx, __shfl_xor(mx, 16, 64));
    mx = fmaxf(mx, __shfl_xor(mx, 32, 64));
    const float nm = fmaxf(m, mx);
    const float alpha = __expf(m - nm);
    float rs = 0.f;
#pragma unroll
    for (int ct = 0; ct < 4; ++ct)
#pragma unroll
      for (int r = 0; r < 4; ++r) {
        const float p = __expf(s[ct][r] - nm);
        s[ct][r] = p;
        rs += p;
      }
    rs += __shfl_xor(rs, 16, 64);
    rs += __shfl_xor(rs, 32, 64);
    ell = ell * alpha + rs;
    m = nm;
#pragma unroll
    for (int dt = 0; dt < 4; ++dt) o[dt] *= alpha;
#pragma unroll
    for (int ct = 0; ct < 4; ++ct)
#pragma unroll
      for (int r = 0; r < 4; ++r)
        p_lds[wave][l16][ct * 16 + lq * 4 + r] = f32_to_bf16(s[ct][r]);
    short8 pf[2];
#pragma unroll
    for (int c = 0; c < 2; ++c)
      pf[c] = *reinterpret_cast<const short8*>(&p_lds[wave][l16][c * 32 + lq * 8]);
#pragma unroll
    for (int dt = 0; dt < 4; ++dt)
#pragma unroll
      for (int c = 0; c < 2; ++c) {
        short8 vf = *reinterpret_cast<const short8*>(vb + (dt * 2 + c) * 512);
        o[dt] = __builtin_amdgcn_mfma_f32_16x16x32_bf16(vf, pf[c], o[dt], 0, 0, 0);
      }
  }

  if (lane < 16) {
    lds_ml[wave][l16][0] = m;
    lds_ml[wave][l16][1] = ell;
  }
  __syncthreads();
  const float m0 = lds_ml[0][l16][0], m1 = lds_ml[1][l16][0];
  const float m2 = lds_ml[2][l16][0], m3 = lds_ml[3][l16][0];
  const float g = fmaxf(fmaxf(m0, m1), fmaxf(m2, m3));
  const float gl = lds_ml[0][l16][1] * __expf(m0 - g) +
                   lds_ml[1][l16][1] * __expf(m1 - g) +
                   lds_ml[2][l16][1] * __expf(m2 - g) +
                   lds_ml[3][l16][1] * __expf(m3 - g);
  const float myscale = __expf(m - g);
  if (wave == 0 && lane < 16) lds_gl[l16] = gl;
#pragma unroll
  for (int dt = 0; dt < 4; ++dt)
#pragma unroll
    for (int r = 0; r < 4; ++r)
      lds_o[wave][l16][dt * 16 + lq * 4 + r] = o[dt][r] * myscale;
  __syncthreads();
#pragma unroll
  for (int j = 0; j < 4; ++j) {
    const int e = tid + 256 * j;
    const int row = e >> 6, col = e & 63;
    const float sum = lds_o[0][row][col] + lds_o[1][row][col] +
                      lds_o[2][row][col] + lds_o[3][row][col];
    out[(qrow + row) * D_KV + col] = sum / lds_gl[row];
  }
}

// ---------------- launch ----------------------------------------------------
extern "C" void kernel_launch(void* const* d_in, const int* in_sizes, int n_in,
                              void* d_out, int out_size, void* d_ws, size_t ws_size,
                              hipStream_t stream) {
  const float* x  = (const float*)d_in[0];
  const float* wq = (const float*)d_in[1];
  const float* bq = (const float*)d_in[2];
  const float* wk = (const float*)d_in[3];
  const float* bk = (const float*)d_in[4];
  const float* wv = (const float*)d_in[5];
  const float* bv = (const float*)d_in[6];
  float* out = (float*)d_out;

  unsigned short* ws    = (unsigned short*)d_ws;
  unsigned short* wfrag = ws;               // 196608 shorts (384KB)
  unsigned short* Qf    = ws + 196608;      // 1048576 shorts
  unsigned short* Kf    = Qf + 1048576;
  unsigned short* Vf    = Kf + 1048576;
  unsigned short* sinkW = Vf + 1048576;     // probe sinks (2MB each)
  unsigned short* sinkX = sinkW + 1048576;

  wcvt_kernel<<<96, 256, 0, stream>>>(wq, wk, wv, wfrag);
  qkv_proj_kernel<<<512, 256, 0, stream>>>(x, wfrag, bq, bk, bv, Qf, Kf, Vf);
  dim3 ag(256, NBATCH);
  attn_kernel<<<ag, 256, 0, stream>>>(Qf, Kf, Vf, out);
  // diagnostics (timed separately by rocprof; do not affect correctness)
  probe_w<<<512, 256, 0, stream>>>(wfrag, sinkW);
  probe_x<<<512, 256, 0, stream>>>(x, sinkX);
}

// Round 15
// 73.449 us; speedup vs baseline: 1.2914x; 1.2914x over previous
//
#include <hip/hip_runtime.h>

typedef __attribute__((ext_vector_type(8))) short short8;
typedef __attribute__((ext_vector_type(4))) float f32x4;

#define D_KV   64
#define SEQ    4096
#define NBATCH 4
#define DMODEL 1024

static __device__ __forceinline__ unsigned short f32_to_bf16(float f) {
  unsigned u = __builtin_bit_cast(unsigned, f);
  u = (u + 0x7FFFu + ((u >> 16) & 1u)) >> 16;  // round-nearest-even
  return (unsigned short)u;
}

// ---------------- kernel 1: weights f32 -> bf16, MFMA-fragment order --------
// wfrag[((nt*32 + ks)*64 + lane)*8 + j] = W_mat[(nt&3)*16 + (lane&15)]
//                                             [ks*32 + (lane>>4)*8 + j]
__global__ __launch_bounds__(256) void wcvt_kernel(
    const float* __restrict__ wq, const float* __restrict__ wk,
    const float* __restrict__ wv, unsigned short* __restrict__ wfrag) {
  const int fid = blockIdx.x * 256 + threadIdx.x;  // 0..24575
  const int nt = fid >> 11, ks = (fid >> 6) & 31, lane = fid & 63;
  const int l16 = lane & 15, lq = lane >> 4;
  const float* w = (nt < 4) ? wq : (nt < 8) ? wk : wv;
  const float* src = w + ((nt & 3) * 16 + l16) * DMODEL + ks * 32 + lq * 8;
  short8 v;
#pragma unroll
  for (int j = 0; j < 8; ++j) v[j] = (short)f32_to_bf16(src[j]);
  *reinterpret_cast<short8*>(wfrag + (long)fid * 8) = v;
}

// ---------------- kernel 2: QKV projection (R12 + NONTEMPORAL x loads) ------
// Theory: streaming 64MB of f32 x through the per-XCD L2s (8MB/XCD vs 4MB
// capacity) evicts the 384KB wfrag working set every chunk -> weight reads
// re-miss to L3 (~192MB L3 traffic = the invariant ~40us). `nt` x loads stop
// the eviction; weights stay L2-resident. Everything else identical to R12.
__global__ __launch_bounds__(256, 1) void qkv_proj_kernel(
    const float* __restrict__ x, const unsigned short* __restrict__ wfrag,
    const float* __restrict__ bq, const float* __restrict__ bk,
    const float* __restrict__ bv,
    unsigned short* __restrict__ Qf, unsigned short* __restrict__ Kf,
    unsigned short* __restrict__ Vf) {
  __shared__ __align__(16) unsigned short lds_x[32 * 1024];  // 64KB swizzled
  const int tid = threadIdx.x, lane = tid & 63, wave = tid >> 6;
  const int l16 = lane & 15, lq = lane >> 4;
  const long rowbase = (long)blockIdx.x * 32;
  unsigned char* lx = (unsigned char*)lds_x;

  // ---- stage x tile (32 rows x 1024 f32), nontemporal coalesced reads -----
  {
    const int srow = tid >> 3, scol = (tid & 7) * 16;
    const float* xrow = x + (rowbase + srow) * DMODEL + scol;
    const int swz = (srow & 7) << 4;
    unsigned char* lbase = lx + srow * 2048;
#pragma unroll
    for (int s = 0; s < 8; ++s) {
      const f32x4 f0 = __builtin_nontemporal_load(
          reinterpret_cast<const f32x4*>(xrow + s * 128));
      const f32x4 f1 = __builtin_nontemporal_load(
          reinterpret_cast<const f32x4*>(xrow + s * 128 + 4));
      const f32x4 f2 = __builtin_nontemporal_load(
          reinterpret_cast<const f32x4*>(xrow + s * 128 + 8));
      const f32x4 f3 = __builtin_nontemporal_load(
          reinterpret_cast<const f32x4*>(xrow + s * 128 + 12));
      short8 s0, s1;
#pragma unroll
      for (int j = 0; j < 4; ++j) {
        s0[j]     = (short)f32_to_bf16(f0[j]);
        s0[4 + j] = (short)f32_to_bf16(f1[j]);
        s1[j]     = (short)f32_to_bf16(f2[j]);
        s1[4 + j] = (short)f32_to_bf16(f3[j]);
      }
      const int bcol = scol * 2 + s * 256;
      *reinterpret_cast<short8*>(lbase + (bcol ^ swz)) = s0;
      *reinterpret_cast<short8*>(lbase + ((bcol + 16) ^ swz)) = s1;
    }
  }
  __syncthreads();

  // ---- K-loop: wave owns nt-trio `wave` for both 16-row subtiles ----------
  const unsigned short* wbase = wfrag + (long)(3 * wave) * 16384 + lane * 8;

  short8 bw[12];
#pragma unroll
  for (int j = 0; j < 12; ++j)
    bw[j] = *reinterpret_cast<const short8*>(
        wbase + (long)(j >> 2) * 16384 + (j & 3) * 512);

  f32x4 acc[3][2];
#pragma unroll
  for (int i = 0; i < 3; ++i)
#pragma unroll
    for (int s = 0; s < 2; ++s) acc[i][s] = (f32x4){0.f, 0.f, 0.f, 0.f};

#pragma unroll
  for (int ck = 0; ck < 8; ++ck) {
    short8 bn[12];
    if (ck < 7) {
#pragma unroll
      for (int j = 0; j < 12; ++j)
        bn[j] = *reinterpret_cast<const short8*>(
            wbase + (long)(j >> 2) * 16384 + ((ck + 1) * 4 + (j & 3)) * 512);
    }
    short8 a[4][2];
#pragma unroll
    for (int kc = 0; kc < 4; ++kc)
#pragma unroll
      for (int sub = 0; sub < 2; ++sub) {
        const int row = sub * 16 + l16;
        a[kc][sub] = *reinterpret_cast<const short8*>(
            lx + row * 2048 +
            (((ck * 4 + kc) * 64 + lq * 16) ^ ((row & 7) << 4)));
      }
#pragma unroll
    for (int kc = 0; kc < 4; ++kc)
#pragma unroll
      for (int i = 0; i < 3; ++i) {
        acc[i][0] = __builtin_amdgcn_mfma_f32_16x16x32_bf16(
            a[kc][0], bw[i * 4 + kc], acc[i][0], 0, 0, 0);
        acc[i][1] = __builtin_amdgcn_mfma_f32_16x16x32_bf16(
            a[kc][1], bw[i * 4 + kc], acc[i][1], 0, 0, 0);
      }
    if (ck < 7) {
#pragma unroll
      for (int j = 0; j < 12; ++j) bw[j] = bn[j];
    }
  }

  // ---- epilogue: LDS-stage in fragment order, coalesced 16B flush ---------
  __syncthreads();
  unsigned short* lo = lds_x;

#pragma unroll
  for (int i = 0; i < 3; ++i) {
    const int nt = 3 * wave + i;
    const int mat = nt >> 2;
    const int dcol = ((nt & 3) << 4) | l16;
    const float bias = (mat == 0 ? bq : mat == 1 ? bk : bv)[dcol];
    const int c = dcol >> 5, lqp = (dcol >> 3) & 3, jj = dcol & 7;
#pragma unroll
    for (int sub = 0; sub < 2; ++sub)
#pragma unroll
      for (int rr = 0; rr < 4; ++rr) {
        const int tl = sub * 16 + lq * 4 + rr;
        const float sum = acc[i][sub][rr] + bias;
        if (mat == 0) {
          lo[(((tl >> 4) * 2 + c) * 64 + lqp * 16 + (tl & 15)) * 8 + jj] =
              f32_to_bf16(sum * 0.125f);  // fold 1/sqrt(64)
        } else if (mat == 1) {
          lo[2048 + (((tl >> 4) * 2 + c) * 64 + lqp * 16 + (tl & 15)) * 8 + jj] =
              f32_to_bf16(sum);
        } else {
          lo[4096 + (nt & 3) * 512 +
             (((tl >> 3) & 3) * 16 + (dcol & 15)) * 8 + (tl & 7)] =
              f32_to_bf16(sum);
        }
      }
  }
  __syncthreads();
  {
    const long qb = (rowbase >> 4) * 1024;
    const int g = tid >> 6;
    const long vb = (((rowbase >> 6) * 4 + g) * 2 + ((rowbase >> 5) & 1)) * 512;
    *reinterpret_cast<short8*>(Qf + qb + tid * 8) =
        *reinterpret_cast<const short8*>(lo + tid * 8);
    *reinterpret_cast<short8*>(Kf + qb + tid * 8) =
        *reinterpret_cast<const short8*>(lo + 2048 + tid * 8);
    *reinterpret_cast<short8*>(Vf + vb + (tid & 63) * 8) =
        *reinterpret_cast<const short8*>(lo + 4096 + tid * 8);
  }
}

// ---------------- kernel 3: causal flash attention (R4-proven, unchanged) ---
__global__ __launch_bounds__(256) void attn_kernel(
    const unsigned short* __restrict__ Qf, const unsigned short* __restrict__ Kf,
    const unsigned short* __restrict__ Vf, float* __restrict__ out) {
  __shared__ __align__(16) unsigned short p_lds[4][16][72];
  __shared__ __align__(16) float lds_o[4][16][68];
  __shared__ float lds_ml[4][16][2];
  __shared__ float lds_gl[16];

  const int tid = threadIdx.x;
  const int lane = tid & 63;
  const int wave = tid >> 6;
  const int l16 = lane & 15, lq = lane >> 4;
  const int b = blockIdx.y;
  const int tile = 255 - blockIdx.x;
  const int qbase = tile * 16;
  const long qrow = (long)b * SEQ + qbase;

  short8 qf[2];
#pragma unroll
  for (int c = 0; c < 2; ++c)
    qf[c] = *reinterpret_cast<const short8*>(
        Qf + ((qrow >> 4) * 2 + c) * 512 + lane * 8);

  f32x4 o[4];
#pragma unroll
  for (int dt = 0; dt < 4; ++dt) o[dt] = (f32x4){0.f, 0.f, 0.f, 0.f};
  float m = -INFINITY, ell = 0.f;

  const long ktile0 = (long)b * 64;
  const int nkv = qbase / 64 + 1;
  for (int kt = wave; kt < nkv; kt += 4) {
    const int kvbase = kt * 64;
    const unsigned short* kb = Kf + (ktile0 + kt) * 4096 + lane * 8;
    const unsigned short* vb = Vf + (ktile0 + kt) * 4096 + lane * 8;
    f32x4 s[4];
#pragma unroll
    for (int ct = 0; ct < 4; ++ct) s[ct] = (f32x4){0.f, 0.f, 0.f, 0.f};
#pragma unroll
    for (int ct = 0; ct < 4; ++ct)
#pragma unroll
      for (int c = 0; c < 2; ++c) {
        short8 kf = *reinterpret_cast<const short8*>(kb + (ct * 2 + c) * 512);
        s[ct] = __builtin_amdgcn_mfma_f32_16x16x32_bf16(kf, qf[c], s[ct], 0, 0, 0);
      }
    if (kt == nkv - 1) {
      const int qg = qbase + l16;
#pragma unroll
      for (int ct = 0; ct < 4; ++ct)
#pragma unroll
        for (int r = 0; r < 4; ++r)
          if (kvbase + ct * 16 + lq * 4 + r > qg) s[ct][r] = -INFINITY;
    }
    float mx = -INFINITY;
#pragma unroll
    for (int ct = 0; ct < 4; ++ct)
#pragma unroll
      for (int r = 0; r < 4; ++r) mx = fmaxf(mx, s[ct][r]);
    mx = fmaxf(mx, __shfl_xor(mx, 16, 64));
    mx = fmaxf(mx, __shfl_xor(mx, 32, 64));
    const float nm = fmaxf(m, mx);
    const float alpha = __expf(m - nm);
    float rs = 0.f;
#pragma unroll
    for (int ct = 0; ct < 4; ++ct)
#pragma unroll
      for (int r = 0; r < 4; ++r) {
        const float p = __expf(s[ct][r] - nm);
        s[ct][r] = p;
        rs += p;
      }
    rs += __shfl_xor(rs, 16, 64);
    rs += __shfl_xor(rs, 32, 64);
    ell = ell * alpha + rs;
    m = nm;
#pragma unroll
    for (int dt = 0; dt < 4; ++dt) o[dt] *= alpha;
#pragma unroll
    for (int ct = 0; ct < 4; ++ct)
#pragma unroll
      for (int r = 0; r < 4; ++r)
        p_lds[wave][l16][ct * 16 + lq * 4 + r] = f32_to_bf16(s[ct][r]);
    short8 pf[2];
#pragma unroll
    for (int c = 0; c < 2; ++c)
      pf[c] = *reinterpret_cast<const short8*>(&p_lds[wave][l16][c * 32 + lq * 8]);
#pragma unroll
    for (int dt = 0; dt < 4; ++dt)
#pragma unroll
      for (int c = 0; c < 2; ++c) {
        short8 vf = *reinterpret_cast<const short8*>(vb + (dt * 2 + c) * 512);
        o[dt] = __builtin_amdgcn_mfma_f32_16x16x32_bf16(vf, pf[c], o[dt], 0, 0, 0);
      }
  }

  if (lane < 16) {
    lds_ml[wave][l16][0] = m;
    lds_ml[wave][l16][1] = ell;
  }
  __syncthreads();
  const float m0 = lds_ml[0][l16][0], m1 = lds_ml[1][l16][0];
  const float m2 = lds_ml[2][l16][0], m3 = lds_ml[3][l16][0];
  const float g = fmaxf(fmaxf(m0, m1), fmaxf(m2, m3));
  const float gl = lds_ml[0][l16][1] * __expf(m0 - g) +
                   lds_ml[1][l16][1] * __expf(m1 - g) +
                   lds_ml[2][l16][1] * __expf(m2 - g) +
                   lds_ml[3][l16][1] * __expf(m3 - g);
  const float myscale = __expf(m - g);
  if (wave == 0 && lane < 16) lds_gl[l16] = gl;
#pragma unroll
  for (int dt = 0; dt < 4; ++dt)
#pragma unroll
    for (int r = 0; r < 4; ++r)
      lds_o[wave][l16][dt * 16 + lq * 4 + r] = o[dt][r] * myscale;
  __syncthreads();
#pragma unroll
  for (int j = 0; j < 4; ++j) {
    const int e = tid + 256 * j;
    const int row = e >> 6, col = e & 63;
    const float sum = lds_o[0][row][col] + lds_o[1][row][col] +
                      lds_o[2][row][col] + lds_o[3][row][col];
    out[(qrow + row) * D_KV + col] = sum / lds_gl[row];
  }
}

// ---------------- launch ----------------------------------------------------
extern "C" void kernel_launch(void* const* d_in, const int* in_sizes, int n_in,
                              void* d_out, int out_size, void* d_ws, size_t ws_size,
                              hipStream_t stream) {
  const float* x  = (const float*)d_in[0];
  const float* wq = (const float*)d_in[1];
  const float* bq = (const float*)d_in[2];
  const float* wk = (const float*)d_in[3];
  const float* bk = (const float*)d_in[4];
  const float* wv = (const float*)d_in[5];
  const float* bv = (const float*)d_in[6];
  float* out = (float*)d_out;

  unsigned short* ws    = (unsigned short*)d_ws;
  unsigned short* wfrag = ws;               // 196608 shorts (384KB)
  unsigned short* Qf    = ws + 196608;      // 1048576 shorts
  unsigned short* Kf    = Qf + 1048576;
  unsigned short* Vf    = Kf + 1048576;

  wcvt_kernel<<<96, 256, 0, stream>>>(wq, wk, wv, wfrag);
  qkv_proj_kernel<<<512, 256, 0, stream>>>(x, wfrag, bq, bk, bv, Qf, Kf, Vf);
  dim3 ag(256, NBATCH);
  attn_kernel<<<ag, 256, 0, stream>>>(Qf, Kf, Vf, out);
}

// Round 16
// 61.126 us; speedup vs baseline: 1.5517x; 1.2016x over previous
//
#include <hip/hip_runtime.h>

typedef __attribute__((ext_vector_type(8))) short short8;
typedef __attribute__((ext_vector_type(4))) float f32x4;

#define D_KV   64
#define SEQ    4096
#define NBATCH 4
#define DMODEL 1024

static __device__ __forceinline__ unsigned short f32_to_bf16(float f) {
  unsigned u = __builtin_bit_cast(unsigned, f);
  u = (u + 0x7FFFu + ((u >> 16) & 1u)) >> 16;  // round-nearest-even
  return (unsigned short)u;
}

// ---------------- kernel 1: weights f32 -> bf16, MFMA-fragment order --------
// wfrag[((nt*32 + ks)*64 + lane)*8 + j] = W_mat[(nt&3)*16 + (lane&15)]
//                                             [ks*32 + (lane>>4)*8 + j]
__global__ __launch_bounds__(256) void wcvt_kernel(
    const float* __restrict__ wq, const float* __restrict__ wk,
    const float* __restrict__ wv, unsigned short* __restrict__ wfrag) {
  const int fid = blockIdx.x * 256 + threadIdx.x;  // 0..24575
  const int nt = fid >> 11, ks = (fid >> 6) & 31, lane = fid & 63;
  const int l16 = lane & 15, lq = lane >> 4;
  const float* w = (nt < 4) ? wq : (nt < 8) ? wk : wv;
  const float* src = w + ((nt & 3) * 16 + l16) * DMODEL + ks * 32 + lq * 8;
  short8 v;
#pragma unroll
  for (int j = 0; j < 8; ++j) v[j] = (short)f32_to_bf16(src[j]);
  *reinterpret_cast<short8*>(wfrag + (long)fid * 8) = v;
}

// ---------------- kernel 2: QKV projection (R8 verbatim — best measured) ----
// 512 blocks x 32 rows x 8 waves: 2 blocks/CU x 8 waves = 4 waves/SIMD.
// Wave w: nt-trio 3*(w&3) for row-subtile (w>>2). x staged per 128-K-chunk
// into double-buffered XOR-swizzled LDS (2 x 8KB).
__global__ __launch_bounds__(512) void qkv_proj_kernel(
    const float* __restrict__ x, const unsigned short* __restrict__ wfrag,
    const float* __restrict__ bq, const float* __restrict__ bk,
    const float* __restrict__ bv,
    unsigned short* __restrict__ Qf, unsigned short* __restrict__ Kf,
    unsigned short* __restrict__ Vf) {
  __shared__ __align__(16) unsigned short lds_x[2 * 32 * 128];  // 2 x 8KB
  const int tid = threadIdx.x, lane = tid & 63, wave = tid >> 6;
  const int l16 = lane & 15, lq = lane >> 4;
  const int sub = wave >> 2;          // 0 or 1: 16-row subtile
  const int trio = wave & 3;          // nt = 3*trio + i
  const long rowbase = (long)blockIdx.x * 32;

  const int r = tid >> 4, oct = tid & 15;
  const float* xrow = x + (rowbase + r) * DMODEL + oct * 8;
  unsigned char* lx = (unsigned char*)lds_x;  // buf b at byte offset b*8192
  const int wr_off = r * 256 + ((oct * 16) ^ ((r & 7) << 4));

  f32x4 acc[3];
#pragma unroll
  for (int i = 0; i < 3; ++i) acc[i] = (f32x4){0.f, 0.f, 0.f, 0.f};

  const unsigned short* wbase = wfrag + (long)(3 * trio) * 16384 + lane * 8;
  const int arow = sub * 16 + l16;

  f32x4 x0, x1;
  x0 = *reinterpret_cast<const f32x4*>(xrow);
  x1 = *reinterpret_cast<const f32x4*>(xrow + 4);
  {
    short8 xs;
#pragma unroll
    for (int j = 0; j < 4; ++j) {
      xs[j] = (short)f32_to_bf16(x0[j]);
      xs[4 + j] = (short)f32_to_bf16(x1[j]);
    }
    *reinterpret_cast<short8*>(lx + wr_off) = xs;
  }
  __syncthreads();

  for (int ck = 0; ck < 8; ++ck) {
    const int curoff = (ck & 1) * 8192;
    const int nxtoff = ((ck & 1) ^ 1) * 8192;
    if (ck < 7) {
      x0 = *reinterpret_cast<const f32x4*>(xrow + (ck + 1) * 128);
      x1 = *reinterpret_cast<const f32x4*>(xrow + (ck + 1) * 128 + 4);
    }
#pragma unroll
    for (int ks = 0; ks < 4; ++ks) {
      const short8 a = *reinterpret_cast<const short8*>(
          lx + curoff + arow * 256 + ((ks * 64 + lq * 16) ^ ((arow & 7) << 4)));
#pragma unroll
      for (int i = 0; i < 3; ++i) {
        const short8 b = *reinterpret_cast<const short8*>(
            wbase + (long)i * 16384 + (ck * 4 + ks) * 512);
        acc[i] = __builtin_amdgcn_mfma_f32_16x16x32_bf16(a, b, acc[i], 0, 0, 0);
      }
    }
    __syncthreads();
    if (ck < 7) {
      short8 xs;
#pragma unroll
      for (int j = 0; j < 4; ++j) {
        xs[j] = (short)f32_to_bf16(x0[j]);
        xs[4 + j] = (short)f32_to_bf16(x1[j]);
      }
      *reinterpret_cast<short8*>(lx + nxtoff + wr_off) = xs;
      __syncthreads();
    }
  }

#pragma unroll
  for (int i = 0; i < 3; ++i) {
    const int nt = 3 * trio + i;
    const int mat = nt >> 2;
    const int dcol = ((nt & 3) << 4) | l16;
    const float bias = (mat == 0 ? bq : mat == 1 ? bk : bv)[dcol];
    const int c = dcol >> 5, lqp = (dcol >> 3) & 3, jj = dcol & 7;
#pragma unroll
    for (int rr = 0; rr < 4; ++rr) {
      const long t = rowbase + sub * 16 + lq * 4 + rr;
      const float sum = acc[i][rr] + bias;
      if (mat == 0) {
        Qf[(((t >> 4) * 2 + c) * 64 + lqp * 16 + (t & 15)) * 8 + jj] =
            f32_to_bf16(sum * 0.125f);  // fold 1/sqrt(64)
      } else if (mat == 1) {
        Kf[((((t >> 6) * 4 + ((t >> 4) & 3)) * 2 + c) * 64 + lqp * 16 +
            (t & 15)) * 8 + jj] = f32_to_bf16(sum);
      } else {
        Vf[((((t >> 6) * 4 + (dcol >> 4)) * 2 + ((t >> 5) & 1)) * 64 +
            ((t >> 3) & 3) * 16 + (dcol & 15)) * 8 + (t & 7)] =
            f32_to_bf16(sum);
      }
    }
  }
}

// ---------------- kernel 3: causal flash attention, 8-wave split-K ----------
// One 16-row Q tile per block; 8 waves split KV round-robin (kt = w, w+8,...)
// -> longest serial chain halves vs the 4-wave version. 8-way LDS combine.
__global__ __launch_bounds__(512) void attn_kernel(
    const unsigned short* __restrict__ Qf, const unsigned short* __restrict__ Kf,
    const unsigned short* __restrict__ Vf, float* __restrict__ out) {
  __shared__ __align__(16) unsigned short p_lds[8][16][72];  // [wave][q][k]
  __shared__ __align__(16) float lds_o[8][16][68];           // [wave][q][d]
  __shared__ float lds_ml[8][16][2];
  __shared__ float lds_gl[16];

  const int tid = threadIdx.x;
  const int lane = tid & 63;
  const int wave = tid >> 6;  // 0..7
  const int l16 = lane & 15, lq = lane >> 4;
  const int b = blockIdx.y;
  const int tile = 255 - blockIdx.x;  // heavy tiles dispatch first
  const int qbase = tile * 16;
  const long qrow = (long)b * SEQ + qbase;

  short8 qf[2];
#pragma unroll
  for (int c = 0; c < 2; ++c)
    qf[c] = *reinterpret_cast<const short8*>(
        Qf + ((qrow >> 4) * 2 + c) * 512 + lane * 8);

  f32x4 o[4];  // O^T: o[dt][r] = O[q=l16][d=dt*16+lq*4+r]
#pragma unroll
  for (int dt = 0; dt < 4; ++dt) o[dt] = (f32x4){0.f, 0.f, 0.f, 0.f};
  float m = -INFINITY, ell = 0.f;  // per-lane state for q = qbase + l16

  const long ktile0 = (long)b * 64;
  const int nkv = qbase / 64 + 1;  // KV tiles of 64 cols
  for (int kt = wave; kt < nkv; kt += 8) {
    const int kvbase = kt * 64;
    const unsigned short* kb = Kf + (ktile0 + kt) * 4096 + lane * 8;
    const unsigned short* vb = Vf + (ktile0 + kt) * 4096 + lane * 8;
    f32x4 s[4];  // S^T: s[ct][r] = S[q=l16][k=kvbase+ct*16+lq*4+r]
#pragma unroll
    for (int ct = 0; ct < 4; ++ct) s[ct] = (f32x4){0.f, 0.f, 0.f, 0.f};
#pragma unroll
    for (int ct = 0; ct < 4; ++ct)
#pragma unroll
      for (int c = 0; c < 2; ++c) {
        short8 kf = *reinterpret_cast<const short8*>(kb + (ct * 2 + c) * 512);
        s[ct] = __builtin_amdgcn_mfma_f32_16x16x32_bf16(kf, qf[c], s[ct], 0, 0, 0);
      }
    if (kt == nkv - 1) {  // only the diagonal tile needs masking
      const int qg = qbase + l16;
#pragma unroll
      for (int ct = 0; ct < 4; ++ct)
#pragma unroll
        for (int r = 0; r < 4; ++r)
          if (kvbase + ct * 16 + lq * 4 + r > qg) s[ct][r] = -INFINITY;
    }
    // lane-local softmax over 16 held k values + 4-lane-group reduce
    float mx = -INFINITY;
#pragma unroll
    for (int ct = 0; ct < 4; ++ct)
#pragma unroll
      for (int r = 0; r < 4; ++r) mx = fmaxf(mx, s[ct][r]);
    mx = fmaxf(mx, __shfl_xor(mx, 16, 64));
    mx = fmaxf(mx, __shfl_xor(mx, 32, 64));
    const float nm = fmaxf(m, mx);
    const float alpha = __expf(m - nm);  // exp(-inf)=0 on first tile
    float rs = 0.f;
#pragma unroll
    for (int ct = 0; ct < 4; ++ct)
#pragma unroll
      for (int r = 0; r < 4; ++r) {
        const float p = __expf(s[ct][r] - nm);
        s[ct][r] = p;
        rs += p;
      }
    rs += __shfl_xor(rs, 16, 64);
    rs += __shfl_xor(rs, 32, 64);
    ell = ell * alpha + rs;
    m = nm;
#pragma unroll
    for (int dt = 0; dt < 4; ++dt) o[dt] *= alpha;
    // P^T (regs) -> p_lds[q][k] -> B-frag for PV. Per-wave buffer, no barrier.
#pragma unroll
    for (int ct = 0; ct < 4; ++ct)
#pragma unroll
      for (int r = 0; r < 4; ++r)
        p_lds[wave][l16][ct * 16 + lq * 4 + r] = f32_to_bf16(s[ct][r]);
    short8 pf[2];
#pragma unroll
    for (int c = 0; c < 2; ++c)
      pf[c] = *reinterpret_cast<const short8*>(&p_lds[wave][l16][c * 32 + lq * 8]);
#pragma unroll
    for (int dt = 0; dt < 4; ++dt)
#pragma unroll
      for (int c = 0; c < 2; ++c) {
        short8 vf = *reinterpret_cast<const short8*>(vb + (dt * 2 + c) * 512);
        o[dt] = __builtin_amdgcn_mfma_f32_16x16x32_bf16(vf, pf[c], o[dt], 0, 0, 0);
      }
  }

  // ---- 8-way cross-wave combine ----
  if (lane < 16) {
    lds_ml[wave][l16][0] = m;
    lds_ml[wave][l16][1] = ell;
  }
  __syncthreads();
  float g = -INFINITY;
#pragma unroll
  for (int w2 = 0; w2 < 8; ++w2) g = fmaxf(g, lds_ml[w2][l16][0]);
  float gl = 0.f;
#pragma unroll
  for (int w2 = 0; w2 < 8; ++w2)
    gl += lds_ml[w2][l16][1] * __expf(lds_ml[w2][l16][0] - g);
  const float myscale = __expf(m - g);
  if (wave == 0 && lane < 16) lds_gl[l16] = gl;
#pragma unroll
  for (int dt = 0; dt < 4; ++dt)
#pragma unroll
    for (int r = 0; r < 4; ++r)
      lds_o[wave][l16][dt * 16 + lq * 4 + r] = o[dt][r] * myscale;
  __syncthreads();
#pragma unroll
  for (int j = 0; j < 2; ++j) {
    const int e = tid + 512 * j;
    const int row = e >> 6, col = e & 63;
    float sum = 0.f;
#pragma unroll
    for (int w2 = 0; w2 < 8; ++w2) sum += lds_o[w2][row][col];
    out[(qrow + row) * D_KV + col] = sum / lds_gl[row];
  }
}

// ---------------- launch ----------------------------------------------------
extern "C" void kernel_launch(void* const* d_in, const int* in_sizes, int n_in,
                              void* d_out, int out_size, void* d_ws, size_t ws_size,
                              hipStream_t stream) {
  const float* x  = (const float*)d_in[0];
  const float* wq = (const float*)d_in[1];
  const float* bq = (const float*)d_in[2];
  const float* wk = (const float*)d_in[3];
  const float* bk = (const float*)d_in[4];
  const float* wv = (const float*)d_in[5];
  const float* bv = (const float*)d_in[6];
  float* out = (float*)d_out;

  unsigned short* ws    = (unsigned short*)d_ws;
  unsigned short* wfrag = ws;               // 196608 shorts (384KB)
  unsigned short* Qf    = ws + 196608;      // 1048576 shorts
  unsigned short* Kf    = Qf + 1048576;
  unsigned short* Vf    = Kf + 1048576;

  wcvt_kernel<<<96, 256, 0, stream>>>(wq, wk, wv, wfrag);
  qkv_proj_kernel<<<512, 512, 0, stream>>>(x, wfrag, bq, bk, bv, Qf, Kf, Vf);
  dim3 ag(256, NBATCH);
  attn_kernel<<<ag, 512, 0, stream>>>(Qf, Kf, Vf, out);
}